// Round 5
// baseline (483.195 us; speedup 1.0000x reference)
//
#include <hip/hip_runtime.h>
#include <math.h>

// ARMA GNN forward: N=100000 nodes, E=1600000 edges, 64 -> 48 -> 40.
// out = log_softmax( relu( A @ (h1@W2) + h1@V2 + b2 ) ), h1 = relu( A @ (x@W1) + x@V1 + b1 )
// A = D^-1/2 (w) D^-1/2.
// R5: 4 sub-buckets/node (atomic same-word contention /4), packed 64-bit
//     (count|w-sum) atomic merges deg into the fill, norm fused into pull_agg.

constexpr int F_IN = 64;
constexpr int HIDDEN = 48;
constexpr int N_CLASS = 40;
constexpr int SUB = 4;        // sub-buckets per node
constexpr int SUB_S = 16;     // slots per sub-bucket (Poisson(4) tail ~0)
constexpr int ELL_S = SUB * SUB_S;  // 64

// ---- bf16x2 pack/unpack ----------------------------------------------------
__device__ __forceinline__ unsigned pack_bf2(float a, float b) {
    unsigned ua = __float_as_uint(a), ub = __float_as_uint(b);
    ua = (ua + 0x7fffu + ((ua >> 16) & 1u)) >> 16;   // RNE
    ub = (ub + 0x7fffu + ((ub >> 16) & 1u)) >> 16;
    return ua | (ub << 16);
}
__device__ __forceinline__ float2 unpack_bf2(unsigned u) {
    return make_float2(__uint_as_float(u << 16), __uint_as_float(u & 0xffff0000u));
}

// ---- dual GEMM body: XWp = packbf16(f(X)@W) ; AGG = f(X)@V + b -------------
// one thread per (node, col-pair); W,V staged in LDS as float2 (bank-conflict-free).
template <int K, int C, bool RELU_IN>
__device__ __forceinline__ void gemm_body(const float* __restrict__ X,
                                          const float* __restrict__ W,
                                          const float* __restrict__ V,
                                          const float* __restrict__ b,
                                          unsigned* __restrict__ XWp,
                                          float* __restrict__ AGG, int N, int bid,
                                          int tid) {
    constexpr int C2 = C / 2;
    __shared__ float2 sW[K * C2];
    __shared__ float2 sV[K * C2];
    for (int i = tid; i < K * C2; i += 256) {
        sW[i] = ((const float2*)W)[i];
        sV[i] = ((const float2*)V)[i];
    }
    __syncthreads();
    int t = bid * 256 + tid;
    if (t >= N * C2) return;
    int n = t / C2, c2 = t - n * C2;
    const float4* xr = (const float4*)(X + (long long)n * K);
    float sw0 = 0.f, sw1 = 0.f, sv0 = 0.f, sv1 = 0.f;
#pragma unroll
    for (int k4 = 0; k4 < K / 4; ++k4) {
        float4 xv4 = xr[k4];
        float xv[4] = {xv4.x, xv4.y, xv4.z, xv4.w};
#pragma unroll
        for (int j = 0; j < 4; ++j) {
            float xv1 = RELU_IN ? fmaxf(xv[j], 0.f) : xv[j];
            int k = k4 * 4 + j;
            float2 wv = sW[k * C2 + c2];
            float2 vv = sV[k * C2 + c2];
            sw0 = fmaf(xv1, wv.x, sw0);
            sw1 = fmaf(xv1, wv.y, sw1);
            sv0 = fmaf(xv1, vv.x, sv0);
            sv1 = fmaf(xv1, vv.y, sv1);
        }
    }
    float2 bb = ((const float2*)b)[c2];
    XWp[t] = pack_bf2(sw0, sw1);
    ((float2*)AGG)[t] = make_float2(sv0 + bb.x, sv1 + bb.y);
}

// ---- fused: fill ELL (blocks < fillBlocks) + layer-1 GEMM (rest) -----------
// cnt4[d*4+s] packs (count << 32) | sum(w * 2^24); one 64-bit atomic per edge.
__global__ void fill_gemm1(const int* __restrict__ src, const int* __restrict__ dst,
                           const float* __restrict__ w,
                           unsigned long long* __restrict__ cnt4,
                           int2* __restrict__ ell, int E, int fillBlocks,
                           const float* __restrict__ X, const float* __restrict__ W,
                           const float* __restrict__ V, const float* __restrict__ b,
                           unsigned* __restrict__ XWp, float* __restrict__ AGG, int N) {
    if ((int)blockIdx.x < fillBlocks) {
        int e = blockIdx.x * 256 + threadIdx.x;
        if (e < E) {
            int d = dst[e];
            float wv = w[e];
            unsigned wq = (unsigned)(wv * 16777216.0f);  // 2^24 fixed point
            int sb = e & (SUB - 1);
            unsigned long long old =
                atomicAdd(&cnt4[(d << 2) | sb], (1ULL << 32) | (unsigned long long)wq);
            unsigned slot = (unsigned)(old >> 32);
            if (slot < SUB_S)  // safety clamp (never hit for this graph)
                ell[(d << 6) + (sb << 4) + slot] = make_int2(src[e], __float_as_int(wv));
        }
    } else {
        gemm_body<F_IN, HIDDEN, false>(X, W, V, b, XWp, AGG, N,
                                       (int)blockIdx.x - fillBlocks, (int)threadIdx.x);
    }
}

// ---- layer-2 GEMM (reads relu(agg1)) ---------------------------------------
__global__ void gemm2_kernel(const float* __restrict__ X, const float* __restrict__ W,
                             const float* __restrict__ V, const float* __restrict__ b,
                             unsigned* __restrict__ XWp, float* __restrict__ AGG, int N) {
    gemm_body<HIDDEN, N_CLASS, true>(X, W, V, b, XWp, AGG, N, (int)blockIdx.x,
                                     (int)threadIdx.x);
}

// ---- dinv[n] = rsqrt(deg), len4[n] = 4x8-bit sub-counts --------------------
__global__ void dinv_len4(const unsigned long long* __restrict__ cnt4,
                          float* __restrict__ dinv, unsigned* __restrict__ len4, int N) {
    int n = blockIdx.x * blockDim.x + threadIdx.x;
    if (n >= N) return;
    const unsigned long long* c = cnt4 + (n << 2);
    unsigned long long c0 = c[0], c1 = c[1], c2 = c[2], c3 = c[3];
    unsigned ws = (unsigned)c0 + (unsigned)c1 + (unsigned)c2 + (unsigned)c3;
    float deg = (float)ws * (1.0f / 16777216.0f);
    dinv[n] = deg > 0.f ? rsqrtf(deg) : 0.f;
    unsigned l0 = min((unsigned)(c0 >> 32), (unsigned)SUB_S);
    unsigned l1 = min((unsigned)(c1 >> 32), (unsigned)SUB_S);
    unsigned l2 = min((unsigned)(c2 >> 32), (unsigned)SUB_S);
    unsigned l3 = min((unsigned)(c3 >> 32), (unsigned)SUB_S);
    len4[n] = l0 | (l1 << 8) | (l2 << 16) | (l3 << 24);
}

// ---- pull: AGG[n][2c2:2c2+2] += sum_j bf2(xWp[src_j][c2]) * dinv[src]*w*dinv[n]
template <int C>
__global__ void pull_agg(const unsigned* __restrict__ XWp, const int2* __restrict__ ell,
                         const unsigned* __restrict__ len4, const float* __restrict__ dinv,
                         float* __restrict__ AGG, int N) {
    constexpr int C2 = C / 2;
    int t = blockIdx.x * blockDim.x + threadIdx.x;
    if (t >= N * C2) return;
    int n = t / C2, c2 = t - n * C2;
    unsigned lp = len4[n];
    float dn = dinv[n];
    const int2* base = ell + (n << 6);
    float2 s = ((const float2*)AGG)[t];
#pragma unroll
    for (int sb = 0; sb < SUB; ++sb) {
        int L = (lp >> (8 * sb)) & 0xff;
        const int2* row = base + (sb << 4);
        for (int j = 0; j < L; ++j) {
            int2 p = row[j];  // broadcast across the C2 threads of this node
            float nr = dinv[p.x] * __int_as_float(p.y) * dn;
            float2 xw = unpack_bf2(XWp[p.x * C2 + c2]);
            s.x = fmaf(xw.x, nr, s.x);
            s.y = fmaf(xw.y, nr, s.y);
        }
    }
    ((float2*)AGG)[t] = s;
}

// ---- out = log_softmax(relu(row)) ------------------------------------------
template <int C>
__global__ void logsoftmax_kernel(const float* __restrict__ in, float* __restrict__ out, int N) {
    int n = blockIdx.x * blockDim.x + threadIdx.x;
    if (n >= N) return;
    const float* r = in + (long long)n * C;
    float m = 0.f;  // relu floor
#pragma unroll
    for (int c = 0; c < C; ++c) m = fmaxf(m, r[c]);
    float s = 0.f;
#pragma unroll
    for (int c = 0; c < C; ++c) s += expf(fmaxf(r[c], 0.f) - m);
    float l = m + logf(s);
    float* o = out + (long long)n * C;
#pragma unroll
    for (int c = 0; c < C; ++c) o[c] = fmaxf(r[c], 0.f) - l;
}

extern "C" void kernel_launch(void* const* d_in, const int* in_sizes, int n_in,
                              void* d_out, int out_size, void* d_ws, size_t ws_size,
                              hipStream_t stream) {
    const float* x  = (const float*)d_in[0];
    const int*   ei = (const int*)d_in[1];
    const float* ew = (const float*)d_in[2];
    const float* W1 = (const float*)d_in[3];
    const float* V1 = (const float*)d_in[4];
    const float* b1 = (const float*)d_in[5];
    const float* W2 = (const float*)d_in[6];
    const float* V2 = (const float*)d_in[7];
    const float* b2 = (const float*)d_in[8];
    float* out = (float*)d_out;

    const int N = in_sizes[0] / F_IN;
    const int E = in_sizes[2];
    const int* src = ei;
    const int* dst = ei + E;

    char* ws = (char*)d_ws;
    size_t off = 0;
    auto carve = [&](size_t bytes) {
        void* p = ws + off;
        off = (off + bytes + 255) & ~size_t(255);
        return p;
    };
    unsigned long long* cnt4 = (unsigned long long*)carve((size_t)N * SUB * 8);
    float*    dinv = (float*)carve((size_t)N * 4);
    unsigned* len4 = (unsigned*)carve((size_t)N * 4);
    int2*     ell  = (int2*)carve((size_t)N * ELL_S * 8);
    unsigned* xW1p = (unsigned*)carve((size_t)N * (HIDDEN / 2) * 4);  // bf16x2
    float*    agg1 = (float*)carve((size_t)N * HIDDEN * 4);
    unsigned* xW2p = xW1p;  // xW1p dead before gemm2 writes
    float*    agg2 = out;   // log_softmax runs in place on d_out

    const int B = 256;
    auto cdiv = [](long long a, long long b) { return (int)((a + b - 1) / b); };

    hipMemsetAsync(cnt4, 0, (size_t)N * SUB * 8, stream);

    // fused: ELL build + layer-1 dual GEMM (independent work)
    const int Gf = cdiv(E, B);
    const int Gg = cdiv((long long)N * (HIDDEN / 2), B);
    fill_gemm1<<<Gf + Gg, B, 0, stream>>>(src, dst, ew, cnt4, ell, E, Gf,
                                          x, W1, V1, b1, xW1p, agg1, N);

    dinv_len4<<<cdiv(N, B), B, 0, stream>>>(cnt4, dinv, len4, N);

    pull_agg<HIDDEN><<<cdiv((long long)N * (HIDDEN / 2), B), B, 0, stream>>>(
        xW1p, ell, len4, dinv, agg1, N);

    gemm2_kernel<<<cdiv((long long)N * (N_CLASS / 2), B), B, 0, stream>>>(
        agg1, W2, V2, b2, xW2p, agg2, N);

    pull_agg<N_CLASS><<<cdiv((long long)N * (N_CLASS / 2), B), B, 0, stream>>>(
        xW2p, ell, len4, dinv, agg2, N);

    logsoftmax_kernel<N_CLASS><<<cdiv(N, B), B, 0, stream>>>(agg2, out, N);
}

// Round 6
// 387.482 us; speedup vs baseline: 1.2470x; 1.2470x over previous
//
#include <hip/hip_runtime.h>
#include <math.h>

// ARMA GNN forward: N=100000 nodes, E=1600000 edges, 64 -> 48 -> 40.
// out = log_softmax( relu( A @ (h1@W2) + h1@V2 + b2 ) ), h1 = relu( A @ (x@W1) + x@V1 + b1 )
// A = D^-1/2 (w) D^-1/2.
// R6: scattered fabric ops (~20 G/s) -> coalesced via 2-level binning:
//     LDS histogram + consecutive-address atomic flush, binned scatter (256B runs),
//     per-bin LDS counting sort -> dst-sorted CSR + rowPtr + dinv. Zero random atomics.

constexpr int F_IN = 64;
constexpr int HIDDEN = 48;
constexpr int N_CLASS = 40;
constexpr int CHUNK = 8192;     // edges per binning block
constexpr int BIN_SHIFT = 9;    // 512 nodes per bin
constexpr int CSR_CAP = 12288;  // LDS stash cap in build_csr (avg bin ~8163, sigma ~90)

// ---- bf16x2 pack/unpack ----------------------------------------------------
__device__ __forceinline__ unsigned pack_bf2(float a, float b) {
    unsigned ua = __float_as_uint(a), ub = __float_as_uint(b);
    ua = (ua + 0x7fffu + ((ua >> 16) & 1u)) >> 16;   // RNE
    ub = (ub + 0x7fffu + ((ub >> 16) & 1u)) >> 16;
    return ua | (ub << 16);
}
__device__ __forceinline__ float2 unpack_bf2(unsigned u) {
    return make_float2(__uint_as_float(u << 16), __uint_as_float(u & 0xffff0000u));
}

// ---- dual GEMM body: XWp = packbf16(f(X)@W) ; AGG = f(X)@V + b -------------
template <int K, int C, bool RELU_IN>
__device__ __forceinline__ void gemm_body(const float* __restrict__ X,
                                          const float* __restrict__ W,
                                          const float* __restrict__ V,
                                          const float* __restrict__ b,
                                          unsigned* __restrict__ XWp,
                                          float* __restrict__ AGG, int N, int bid,
                                          int tid) {
    constexpr int C2 = C / 2;
    __shared__ float2 sW[K * C2];
    __shared__ float2 sV[K * C2];
    for (int i = tid; i < K * C2; i += 256) {
        sW[i] = ((const float2*)W)[i];
        sV[i] = ((const float2*)V)[i];
    }
    __syncthreads();
    int t = bid * 256 + tid;
    if (t >= N * C2) return;
    int n = t / C2, c2 = t - n * C2;
    const float4* xr = (const float4*)(X + (long long)n * K);
    float sw0 = 0.f, sw1 = 0.f, sv0 = 0.f, sv1 = 0.f;
#pragma unroll
    for (int k4 = 0; k4 < K / 4; ++k4) {
        float4 xv4 = xr[k4];
        float xv[4] = {xv4.x, xv4.y, xv4.z, xv4.w};
#pragma unroll
        for (int j = 0; j < 4; ++j) {
            float xv1 = RELU_IN ? fmaxf(xv[j], 0.f) : xv[j];
            int k = k4 * 4 + j;
            float2 wv = sW[k * C2 + c2];
            float2 vv = sV[k * C2 + c2];
            sw0 = fmaf(xv1, wv.x, sw0);
            sw1 = fmaf(xv1, wv.y, sw1);
            sv0 = fmaf(xv1, vv.x, sv0);
            sv1 = fmaf(xv1, vv.y, sv1);
        }
    }
    float2 bb = ((const float2*)b)[c2];
    XWp[t] = pack_bf2(sw0, sw1);
    ((float2*)AGG)[t] = make_float2(sv0 + bb.x, sv1 + bb.y);
}

// ---- phase A: bin counting (LDS hist -> consecutive-addr atomics) + gemm1 --
__global__ void count_gemm1(const int* __restrict__ dst, int* __restrict__ binCnt,
                            int E, int nCountBlocks,
                            const float* __restrict__ X, const float* __restrict__ W,
                            const float* __restrict__ V, const float* __restrict__ b,
                            unsigned* __restrict__ XWp, float* __restrict__ AGG, int N) {
    if ((int)blockIdx.x < nCountBlocks) {
        __shared__ int hist[256];
        int tid = threadIdx.x;
        hist[tid] = 0;
        __syncthreads();
        long long e0 = (long long)blockIdx.x * CHUNK;
        int M = (int)min((long long)CHUNK, (long long)E - e0);
        for (int i = tid; i < M; i += 256) atomicAdd(&hist[dst[e0 + i] >> BIN_SHIFT], 1);
        __syncthreads();
        atomicAdd(&binCnt[tid], hist[tid]);  // lanes hit consecutive words -> coalesced
    } else {
        gemm_body<F_IN, HIDDEN, false>(X, W, V, b, XWp, AGG, N,
                                       (int)blockIdx.x - nCountBlocks, (int)threadIdx.x);
    }
}

// ---- phase B: exclusive scan of 256 bin counts -----------------------------
__global__ void scan_bins(const int* __restrict__ binCnt, int* __restrict__ binStart,
                          int* __restrict__ binCursor, int* __restrict__ rowPtr,
                          int E, int N) {
    __shared__ int s[256];
    int t = threadIdx.x;
    int v = binCnt[t];
    s[t] = v;
    __syncthreads();
#pragma unroll
    for (int o = 1; o < 256; o <<= 1) {
        int u = (t >= o) ? s[t - o] : 0;
        __syncthreads();
        s[t] += u;
        __syncthreads();
    }
    int excl = s[t] - v;
    binStart[t] = excl;
    binCursor[t] = excl;
    if (t == 0) {
        binStart[256] = E;
        rowPtr[N] = E;
    }
}

// ---- phase C: scatter edges into bin regions (256B runs, line-coalesced) ---
// payload: x = (dstLocal<<17)|src (9+17 bits), y = w bits
__global__ void binscatter(const int* __restrict__ src, const int* __restrict__ dst,
                           const float* __restrict__ w, int* __restrict__ binCursor,
                           int2* __restrict__ binned, int E) {
    __shared__ int sx[CHUNK];
    __shared__ int sw[CHUNK];
    __shared__ unsigned char sbin[CHUNK];
    __shared__ int hist[256];
    int tid = threadIdx.x;
    hist[tid] = 0;
    __syncthreads();
    long long e0 = (long long)blockIdx.x * CHUNK;
    int M = (int)min((long long)CHUNK, (long long)E - e0);
    for (int i = tid; i < M; i += 256) {
        int d = dst[e0 + i];
        int bn = d >> BIN_SHIFT;
        sx[i] = ((d & 511) << 17) | src[e0 + i];
        sw[i] = __float_as_int(w[e0 + i]);
        sbin[i] = (unsigned char)bn;
        atomicAdd(&hist[bn], 1);
    }
    __syncthreads();
    int base = atomicAdd(&binCursor[tid], hist[tid]);  // consecutive words -> coalesced
    __syncthreads();
    hist[tid] = base;  // reuse as global cursor
    __syncthreads();
    for (int i = tid; i < M; i += 256) {
        int p = atomicAdd(&hist[sbin[i]], 1);  // LDS atomic, cheap
        binned[p] = make_int2(sx[i], sw[i]);
    }
}

// ---- phase D: per-bin LDS counting sort -> CSR + rowPtr + dinv -------------
__global__ __launch_bounds__(512) void build_csr(const int2* __restrict__ binned,
                                                 const int* __restrict__ binStart,
                                                 int* __restrict__ rowPtr,
                                                 float* __restrict__ dinv,
                                                 int2* __restrict__ csr, int N) {
    __shared__ int sx[CSR_CAP];
    __shared__ int sw[CSR_CAP];
    __shared__ int cntL[512];
    __shared__ float degL[512];
    __shared__ int scanL[512];
    int b = blockIdx.x, tid = threadIdx.x;
    int e0 = binStart[b], e1 = binStart[b + 1], M = e1 - e0;
    cntL[tid] = 0;
    degL[tid] = 0.f;
    __syncthreads();
    bool fits = (M <= CSR_CAP);
    for (int i = tid; i < M; i += 512) {
        int2 p = binned[e0 + i];
        if (fits) { sx[i] = p.x; sw[i] = p.y; }
        int dl = ((unsigned)p.x) >> 17;
        atomicAdd(&cntL[dl], 1);
        atomicAdd(&degL[dl], __int_as_float(p.y));
    }
    __syncthreads();
    int v = cntL[tid];
    scanL[tid] = v;
    __syncthreads();
#pragma unroll
    for (int o = 1; o < 512; o <<= 1) {
        int u = (tid >= o) ? scanL[tid - o] : 0;
        __syncthreads();
        scanL[tid] += u;
        __syncthreads();
    }
    int excl = scanL[tid] - v;
    int node = (b << BIN_SHIFT) + tid;
    if (node < N) {
        rowPtr[node] = e0 + excl;
        float dg = degL[tid];
        dinv[node] = dg > 0.f ? rsqrtf(dg) : 0.f;
    }
    cntL[tid] = e0 + excl;  // reuse as global write cursor
    __syncthreads();
    for (int i = tid; i < M; i += 512) {
        int px, pw;
        if (fits) { px = sx[i]; pw = sw[i]; }
        else { int2 p = binned[e0 + i]; px = p.x; pw = p.y; }
        int dl = ((unsigned)px) >> 17;
        int pos = atomicAdd(&cntL[dl], 1);  // LDS atomic
        csr[pos] = make_int2(px & 0x1FFFF, pw);  // (src, w) sorted by dst
    }
}

// ---- layer-2 GEMM (reads relu(agg1)) ---------------------------------------
__global__ void gemm2_kernel(const float* __restrict__ X, const float* __restrict__ W,
                             const float* __restrict__ V, const float* __restrict__ b,
                             unsigned* __restrict__ XWp, float* __restrict__ AGG, int N) {
    gemm_body<HIDDEN, N_CLASS, true>(X, W, V, b, XWp, AGG, N, (int)blockIdx.x,
                                     (int)threadIdx.x);
}

// ---- pull: AGG[n][2c2:2c2+2] += sum_j bf2(xWp[src_j][c2]) * dinv[src]*w*dinv[n]
template <int C>
__global__ void pull_agg(const unsigned* __restrict__ XWp, const int2* __restrict__ csr,
                         const int* __restrict__ rowPtr, const float* __restrict__ dinv,
                         float* __restrict__ AGG, int N) {
    constexpr int C2 = C / 2;
    int t = blockIdx.x * blockDim.x + threadIdx.x;
    if (t >= N * C2) return;
    int n = t / C2, c2 = t - n * C2;
    int beg = rowPtr[n], end = rowPtr[n + 1];
    float dn = dinv[n];
    float2 s = ((const float2*)AGG)[t];
    for (int j = beg; j < end; ++j) {
        int2 p = csr[j];  // broadcast across the C2 threads of this node
        float nr = dinv[p.x] * __int_as_float(p.y) * dn;
        float2 xw = unpack_bf2(XWp[p.x * C2 + c2]);
        s.x = fmaf(xw.x, nr, s.x);
        s.y = fmaf(xw.y, nr, s.y);
    }
    ((float2*)AGG)[t] = s;
}

// ---- out = log_softmax(relu(row)) ------------------------------------------
template <int C>
__global__ void logsoftmax_kernel(const float* __restrict__ in, float* __restrict__ out, int N) {
    int n = blockIdx.x * blockDim.x + threadIdx.x;
    if (n >= N) return;
    const float* r = in + (long long)n * C;
    float m = 0.f;  // relu floor
#pragma unroll
    for (int c = 0; c < C; ++c) m = fmaxf(m, r[c]);
    float s = 0.f;
#pragma unroll
    for (int c = 0; c < C; ++c) s += expf(fmaxf(r[c], 0.f) - m);
    float l = m + logf(s);
    float* o = out + (long long)n * C;
#pragma unroll
    for (int c = 0; c < C; ++c) o[c] = fmaxf(r[c], 0.f) - l;
}

extern "C" void kernel_launch(void* const* d_in, const int* in_sizes, int n_in,
                              void* d_out, int out_size, void* d_ws, size_t ws_size,
                              hipStream_t stream) {
    const float* x  = (const float*)d_in[0];
    const int*   ei = (const int*)d_in[1];
    const float* ew = (const float*)d_in[2];
    const float* W1 = (const float*)d_in[3];
    const float* V1 = (const float*)d_in[4];
    const float* b1 = (const float*)d_in[5];
    const float* W2 = (const float*)d_in[6];
    const float* V2 = (const float*)d_in[7];
    const float* b2 = (const float*)d_in[8];
    float* out = (float*)d_out;

    const int N = in_sizes[0] / F_IN;
    const int E = in_sizes[2];
    const int* src = ei;
    const int* dst = ei + E;

    char* ws = (char*)d_ws;
    size_t off = 0;
    auto carve = [&](size_t bytes) {
        void* p = ws + off;
        off = (off + bytes + 255) & ~size_t(255);
        return p;
    };
    int*      binCnt    = (int*)carve(256 * 4);
    int*      binStart  = (int*)carve(257 * 4);
    int*      binCursor = (int*)carve(256 * 4);
    int*      rowPtr    = (int*)carve((size_t)(N + 1) * 4);
    float*    dinv      = (float*)carve((size_t)N * 4);
    int2*     binned    = (int2*)carve((size_t)E * 8);
    int2*     csr       = (int2*)carve((size_t)E * 8);
    unsigned* xW1p      = (unsigned*)carve((size_t)N * (HIDDEN / 2) * 4);  // bf16x2
    float*    agg1      = (float*)carve((size_t)N * HIDDEN * 4);
    unsigned* xW2p      = xW1p;  // xW1p dead before gemm2 writes
    float*    agg2      = out;   // log_softmax runs in place on d_out

    const int B = 256;
    auto cdiv = [](long long a, long long b) { return (int)((a + b - 1) / b); };
    const int nChunks = cdiv(E, CHUNK);            // 196
    const int nBins = (N + (1 << BIN_SHIFT) - 1) >> BIN_SHIFT;  // 196

    hipMemsetAsync(binCnt, 0, 256 * 4, stream);

    const int Gg = cdiv((long long)N * (HIDDEN / 2), B);
    count_gemm1<<<nChunks + Gg, B, 0, stream>>>(dst, binCnt, E, nChunks,
                                                x, W1, V1, b1, xW1p, agg1, N);
    scan_bins<<<1, 256, 0, stream>>>(binCnt, binStart, binCursor, rowPtr, E, N);
    binscatter<<<nChunks, B, 0, stream>>>(src, dst, ew, binCursor, binned, E);
    build_csr<<<nBins, 512, 0, stream>>>(binned, binStart, rowPtr, dinv, csr, N);

    pull_agg<HIDDEN><<<cdiv((long long)N * (HIDDEN / 2), B), B, 0, stream>>>(
        xW1p, csr, rowPtr, dinv, agg1, N);

    gemm2_kernel<<<cdiv((long long)N * (N_CLASS / 2), B), B, 0, stream>>>(
        agg1, W2, V2, b2, xW2p, agg2, N);

    pull_agg<N_CLASS><<<cdiv((long long)N * (N_CLASS / 2), B), B, 0, stream>>>(
        xW2p, csr, rowPtr, dinv, agg2, N);

    logsoftmax_kernel<N_CLASS><<<cdiv(N, B), B, 0, stream>>>(agg2, out, N);
}

// Round 7
// 335.737 us; speedup vs baseline: 1.4392x; 1.1541x over previous
//
#include <hip/hip_runtime.h>
#include <math.h>

// ARMA GNN forward: N=100000 nodes, E=1600000 edges, 64 -> 48 -> 40.
// out = log_softmax( relu( A @ (h1@W2) + h1@V2 + b2 ) ), h1 = relu( A @ (x@W1) + x@V1 + b1 )
// A = D^-1/2 (w) D^-1/2.
// R7: pull_agg latency chain cut: dinv[src] folded into xWp (pre-scaled),
//     dinv[dst] folded into csr.w at build; 4-way unrolled independent gathers;
//     log_softmax fused into layer-2 pull.

constexpr int F_IN = 64;
constexpr int HIDDEN = 48;
constexpr int N_CLASS = 40;
constexpr int CHUNK = 8192;     // edges per binning block
constexpr int BIN_SHIFT = 9;    // 512 nodes per bin
constexpr int CSR_CAP = 12288;  // LDS stash cap in build_csr (avg bin ~8163)

// ---- bf16x2 pack/unpack ----------------------------------------------------
__device__ __forceinline__ unsigned pack_bf2(float a, float b) {
    unsigned ua = __float_as_uint(a), ub = __float_as_uint(b);
    ua = (ua + 0x7fffu + ((ua >> 16) & 1u)) >> 16;   // RNE
    ub = (ub + 0x7fffu + ((ub >> 16) & 1u)) >> 16;
    return ua | (ub << 16);
}
__device__ __forceinline__ float2 unpack_bf2(unsigned u) {
    return make_float2(__uint_as_float(u << 16), __uint_as_float(u & 0xffff0000u));
}

// ---- dual GEMM body: XWp = packbf16(f(X)@W [*dinv]) ; AGG = f(X)@V + b -----
template <int K, int C, bool RELU_IN, bool SCALE>
__device__ __forceinline__ void gemm_body(const float* __restrict__ X,
                                          const float* __restrict__ W,
                                          const float* __restrict__ V,
                                          const float* __restrict__ b,
                                          const float* __restrict__ dinv,
                                          unsigned* __restrict__ XWp,
                                          float* __restrict__ AGG, int N, int bid,
                                          int tid) {
    constexpr int C2 = C / 2;
    __shared__ float2 sW[K * C2];
    __shared__ float2 sV[K * C2];
    for (int i = tid; i < K * C2; i += 256) {
        sW[i] = ((const float2*)W)[i];
        sV[i] = ((const float2*)V)[i];
    }
    __syncthreads();
    int t = bid * 256 + tid;
    if (t >= N * C2) return;
    int n = t / C2, c2 = t - n * C2;
    const float4* xr = (const float4*)(X + (long long)n * K);
    float sw0 = 0.f, sw1 = 0.f, sv0 = 0.f, sv1 = 0.f;
#pragma unroll
    for (int k4 = 0; k4 < K / 4; ++k4) {
        float4 xv4 = xr[k4];
        float xv[4] = {xv4.x, xv4.y, xv4.z, xv4.w};
#pragma unroll
        for (int j = 0; j < 4; ++j) {
            float xv1 = RELU_IN ? fmaxf(xv[j], 0.f) : xv[j];
            int k = k4 * 4 + j;
            float2 wv = sW[k * C2 + c2];
            float2 vv = sV[k * C2 + c2];
            sw0 = fmaf(xv1, wv.x, sw0);
            sw1 = fmaf(xv1, wv.y, sw1);
            sv0 = fmaf(xv1, vv.x, sv0);
            sv1 = fmaf(xv1, vv.y, sv1);
        }
    }
    float2 bb = ((const float2*)b)[c2];
    float dv = SCALE ? dinv[n] : 1.0f;
    XWp[t] = pack_bf2(sw0 * dv, sw1 * dv);
    ((float2*)AGG)[t] = make_float2(sv0 + bb.x, sv1 + bb.y);
}

// ---- phase A: bin counting (LDS hist -> consecutive-addr atomics) + gemm1 --
__global__ void count_gemm1(const int* __restrict__ dst, int* __restrict__ binCnt,
                            int E, int nCountBlocks,
                            const float* __restrict__ X, const float* __restrict__ W,
                            const float* __restrict__ V, const float* __restrict__ b,
                            unsigned* __restrict__ XWp, float* __restrict__ AGG, int N) {
    if ((int)blockIdx.x < nCountBlocks) {
        __shared__ int hist[256];
        int tid = threadIdx.x;
        hist[tid] = 0;
        __syncthreads();
        long long e0 = (long long)blockIdx.x * CHUNK;
        int M = (int)min((long long)CHUNK, (long long)E - e0);
        for (int i = tid; i < M; i += 256) atomicAdd(&hist[dst[e0 + i] >> BIN_SHIFT], 1);
        __syncthreads();
        atomicAdd(&binCnt[tid], hist[tid]);  // consecutive words -> coalesced
    } else {
        gemm_body<F_IN, HIDDEN, false, false>(X, W, V, b, nullptr, XWp, AGG, N,
                                              (int)blockIdx.x - nCountBlocks,
                                              (int)threadIdx.x);
    }
}

// ---- phase B: exclusive scan of 256 bin counts -----------------------------
__global__ void scan_bins(const int* __restrict__ binCnt, int* __restrict__ binStart,
                          int* __restrict__ binCursor, int* __restrict__ rowPtr,
                          int E, int N) {
    __shared__ int s[256];
    int t = threadIdx.x;
    int v = binCnt[t];
    s[t] = v;
    __syncthreads();
#pragma unroll
    for (int o = 1; o < 256; o <<= 1) {
        int u = (t >= o) ? s[t - o] : 0;
        __syncthreads();
        s[t] += u;
        __syncthreads();
    }
    int excl = s[t] - v;
    binStart[t] = excl;
    binCursor[t] = excl;
    if (t == 0) {
        binStart[256] = E;
        rowPtr[N] = E;
    }
}

// ---- phase C: scatter edges into bin regions (256B runs, line-coalesced) ---
// payload: x = (dstLocal<<17)|src (9+17 bits), y = w bits
__global__ void binscatter(const int* __restrict__ src, const int* __restrict__ dst,
                           const float* __restrict__ w, int* __restrict__ binCursor,
                           int2* __restrict__ binned, int E) {
    __shared__ int sx[CHUNK];
    __shared__ int sw[CHUNK];
    __shared__ unsigned char sbin[CHUNK];
    __shared__ int hist[256];
    int tid = threadIdx.x;
    hist[tid] = 0;
    __syncthreads();
    long long e0 = (long long)blockIdx.x * CHUNK;
    int M = (int)min((long long)CHUNK, (long long)E - e0);
    for (int i = tid; i < M; i += 256) {
        int d = dst[e0 + i];
        int bn = d >> BIN_SHIFT;
        sx[i] = ((d & 511) << 17) | src[e0 + i];
        sw[i] = __float_as_int(w[e0 + i]);
        sbin[i] = (unsigned char)bn;
        atomicAdd(&hist[bn], 1);
    }
    __syncthreads();
    int base = atomicAdd(&binCursor[tid], hist[tid]);  // consecutive words -> coalesced
    __syncthreads();
    hist[tid] = base;  // reuse as global cursor
    __syncthreads();
    for (int i = tid; i < M; i += 256) {
        int p = atomicAdd(&hist[sbin[i]], 1);  // LDS atomic, cheap
        binned[p] = make_int2(sx[i], sw[i]);
    }
}

// ---- phase D: per-bin LDS counting sort -> CSR (w pre-scaled by dinv[dst]) -
__global__ __launch_bounds__(512) void build_csr(const int2* __restrict__ binned,
                                                 const int* __restrict__ binStart,
                                                 int* __restrict__ rowPtr,
                                                 float* __restrict__ dinv,
                                                 int2* __restrict__ csr, int N) {
    __shared__ int sx[CSR_CAP];
    __shared__ int sw[CSR_CAP];
    __shared__ int cntL[512];
    __shared__ float degL[512];  // deg sums, then dinv values
    __shared__ int scanL[512];
    int b = blockIdx.x, tid = threadIdx.x;
    int e0 = binStart[b], e1 = binStart[b + 1], M = e1 - e0;
    cntL[tid] = 0;
    degL[tid] = 0.f;
    __syncthreads();
    bool fits = (M <= CSR_CAP);
    for (int i = tid; i < M; i += 512) {
        int2 p = binned[e0 + i];
        if (fits) { sx[i] = p.x; sw[i] = p.y; }
        int dl = ((unsigned)p.x) >> 17;
        atomicAdd(&cntL[dl], 1);
        atomicAdd(&degL[dl], __int_as_float(p.y));
    }
    __syncthreads();
    int v = cntL[tid];
    scanL[tid] = v;
    __syncthreads();
#pragma unroll
    for (int o = 1; o < 512; o <<= 1) {
        int u = (tid >= o) ? scanL[tid - o] : 0;
        __syncthreads();
        scanL[tid] += u;
        __syncthreads();
    }
    int excl = scanL[tid] - v;
    int node = (b << BIN_SHIFT) + tid;
    float dg = degL[tid];
    float dv = dg > 0.f ? rsqrtf(dg) : 0.f;
    if (node < N) {
        rowPtr[node] = e0 + excl;
        dinv[node] = dv;
    }
    cntL[tid] = e0 + excl;  // reuse as global write cursor
    degL[tid] = dv;         // reuse as dinv table for write phase
    __syncthreads();
    for (int i = tid; i < M; i += 512) {
        int px, pw;
        if (fits) { px = sx[i]; pw = sw[i]; }
        else { int2 p = binned[e0 + i]; px = p.x; pw = p.y; }
        int dl = ((unsigned)px) >> 17;
        int pos = atomicAdd(&cntL[dl], 1);  // LDS atomic
        float wn = __int_as_float(pw) * degL[dl];  // fold dinv[dst] in now
        csr[pos] = make_int2(px & 0x1FFFF, __float_as_int(wn));
    }
}

// ---- xWp[n][*] *= dinv[n]  (layer-1; layer-2 scaling fused in gemm2) -------
template <int C2>
__global__ void scale_xw(unsigned* __restrict__ XWp, const float* __restrict__ dinv,
                         int total) {
    int t = blockIdx.x * blockDim.x + threadIdx.x;
    if (t >= total) return;
    float dv = dinv[t / C2];
    float2 u = unpack_bf2(XWp[t]);
    XWp[t] = pack_bf2(u.x * dv, u.y * dv);
}

// ---- layer-2 GEMM (reads relu(agg1), writes dinv-scaled xW2p) --------------
__global__ void gemm2_kernel(const float* __restrict__ X, const float* __restrict__ W,
                             const float* __restrict__ V, const float* __restrict__ b,
                             const float* __restrict__ dinv,
                             unsigned* __restrict__ XWp, float* __restrict__ AGG, int N) {
    gemm_body<HIDDEN, N_CLASS, true, true>(X, W, V, b, dinv, XWp, AGG, N,
                                           (int)blockIdx.x, (int)threadIdx.x);
}

// ---- 4-way unrolled row accumulate (xWp pre-scaled; csr.y = w*dinv[dst]) ---
template <int C2>
__device__ __forceinline__ float2 row_accum(const unsigned* __restrict__ XWp,
                                            const int2* __restrict__ csr, int j,
                                            int end, int c2, float2 s) {
    for (; j + 4 <= end; j += 4) {
        int2 p0 = csr[j], p1 = csr[j + 1], p2 = csr[j + 2], p3 = csr[j + 3];
        unsigned u0 = XWp[p0.x * C2 + c2];
        unsigned u1 = XWp[p1.x * C2 + c2];
        unsigned u2 = XWp[p2.x * C2 + c2];
        unsigned u3 = XWp[p3.x * C2 + c2];
        float2 x0 = unpack_bf2(u0), x1 = unpack_bf2(u1);
        float2 x2 = unpack_bf2(u2), x3 = unpack_bf2(u3);
        float n0 = __int_as_float(p0.y), n1 = __int_as_float(p1.y);
        float n2 = __int_as_float(p2.y), n3 = __int_as_float(p3.y);
        s.x = fmaf(x0.x, n0, s.x); s.y = fmaf(x0.y, n0, s.y);
        s.x = fmaf(x1.x, n1, s.x); s.y = fmaf(x1.y, n1, s.y);
        s.x = fmaf(x2.x, n2, s.x); s.y = fmaf(x2.y, n2, s.y);
        s.x = fmaf(x3.x, n3, s.x); s.y = fmaf(x3.y, n3, s.y);
    }
    for (; j < end; ++j) {
        int2 p = csr[j];
        float2 xw = unpack_bf2(XWp[p.x * C2 + c2]);
        float nr = __int_as_float(p.y);
        s.x = fmaf(xw.x, nr, s.x);
        s.y = fmaf(xw.y, nr, s.y);
    }
    return s;
}

// ---- layer-1 pull: AGG[n] += sum_j xWp[src_j] * nrm_j ----------------------
template <int C>
__global__ void pull_agg(const unsigned* __restrict__ XWp, const int2* __restrict__ csr,
                         const int* __restrict__ rowPtr, float* __restrict__ AGG, int N) {
    constexpr int C2 = C / 2;
    int t = blockIdx.x * blockDim.x + threadIdx.x;
    if (t >= N * C2) return;
    int n = t / C2, c2 = t - n * C2;
    float2 s = ((const float2*)AGG)[t];
    s = row_accum<C2>(XWp, csr, rowPtr[n], rowPtr[n + 1], c2, s);
    ((float2*)AGG)[t] = s;
}

// ---- layer-2 pull fused with log_softmax(relu(.)) --------------------------
// block = 320 threads = 16 nodes x 20 col-pairs.
__global__ __launch_bounds__(320) void pull_ls(const unsigned* __restrict__ XWp,
                                               const int2* __restrict__ csr,
                                               const int* __restrict__ rowPtr,
                                               const float* __restrict__ AGGin,
                                               float* __restrict__ out, int N) {
    constexpr int C2 = N_CLASS / 2;  // 20
    __shared__ float2 sbuf[16 * C2];
    __shared__ float sl[16];
    int tid = threadIdx.x;
    int nl = tid / C2, c2 = tid - nl * C2;
    int n = blockIdx.x * 16 + nl;
    float2 s = make_float2(0.f, 0.f);
    if (n < N) {
        s = ((const float2*)AGGin)[n * C2 + c2];
        s = row_accum<C2>(XWp, csr, rowPtr[n], rowPtr[n + 1], c2, s);
    }
    sbuf[tid] = s;
    __syncthreads();
    if (tid < 16) {
        const float2* row = sbuf + tid * C2;
        float m = 0.f;  // relu floor
        for (int k = 0; k < C2; ++k) {
            float2 v = row[k];
            m = fmaxf(m, fmaxf(v.x, v.y));
        }
        float sum = 0.f;
        for (int k = 0; k < C2; ++k) {
            float2 v = row[k];
            sum += expf(fmaxf(v.x, 0.f) - m) + expf(fmaxf(v.y, 0.f) - m);
        }
        sl[tid] = m + logf(sum);
    }
    __syncthreads();
    if (n < N) {
        float l = sl[nl];
        ((float2*)out)[n * C2 + c2] =
            make_float2(fmaxf(s.x, 0.f) - l, fmaxf(s.y, 0.f) - l);
    }
}

extern "C" void kernel_launch(void* const* d_in, const int* in_sizes, int n_in,
                              void* d_out, int out_size, void* d_ws, size_t ws_size,
                              hipStream_t stream) {
    const float* x  = (const float*)d_in[0];
    const int*   ei = (const int*)d_in[1];
    const float* ew = (const float*)d_in[2];
    const float* W1 = (const float*)d_in[3];
    const float* V1 = (const float*)d_in[4];
    const float* b1 = (const float*)d_in[5];
    const float* W2 = (const float*)d_in[6];
    const float* V2 = (const float*)d_in[7];
    const float* b2 = (const float*)d_in[8];
    float* out = (float*)d_out;

    const int N = in_sizes[0] / F_IN;
    const int E = in_sizes[2];
    const int* src = ei;
    const int* dst = ei + E;

    char* ws = (char*)d_ws;
    size_t off = 0;
    auto carve = [&](size_t bytes) {
        void* p = ws + off;
        off = (off + bytes + 255) & ~size_t(255);
        return p;
    };
    int*      binCnt    = (int*)carve(256 * 4);
    int*      binStart  = (int*)carve(257 * 4);
    int*      binCursor = (int*)carve(256 * 4);
    int*      rowPtr    = (int*)carve((size_t)(N + 1) * 4);
    float*    dinv      = (float*)carve((size_t)N * 4);
    int2*     binned    = (int2*)carve((size_t)E * 8);
    int2*     csr       = (int2*)carve((size_t)E * 8);
    unsigned* xW1p      = (unsigned*)carve((size_t)N * (HIDDEN / 2) * 4);  // bf16x2
    float*    agg1      = (float*)carve((size_t)N * HIDDEN * 4);
    float*    agg2      = (float*)carve((size_t)N * N_CLASS * 4);
    unsigned* xW2p      = xW1p;  // xW1p dead before gemm2 writes

    const int B = 256;
    auto cdiv = [](long long a, long long b) { return (int)((a + b - 1) / b); };
    const int nChunks = cdiv(E, CHUNK);
    const int nBins = (N + (1 << BIN_SHIFT) - 1) >> BIN_SHIFT;

    hipMemsetAsync(binCnt, 0, 256 * 4, stream);

    const int Gg = cdiv((long long)N * (HIDDEN / 2), B);
    count_gemm1<<<nChunks + Gg, B, 0, stream>>>(dst, binCnt, E, nChunks,
                                                x, W1, V1, b1, xW1p, agg1, N);
    scan_bins<<<1, 256, 0, stream>>>(binCnt, binStart, binCursor, rowPtr, E, N);
    binscatter<<<nChunks, B, 0, stream>>>(src, dst, ew, binCursor, binned, E);
    build_csr<<<nBins, 512, 0, stream>>>(binned, binStart, rowPtr, dinv, csr, N);

    scale_xw<HIDDEN / 2><<<cdiv((long long)N * (HIDDEN / 2), B), B, 0, stream>>>(
        xW1p, dinv, N * (HIDDEN / 2));

    pull_agg<HIDDEN><<<cdiv((long long)N * (HIDDEN / 2), B), B, 0, stream>>>(
        xW1p, csr, rowPtr, agg1, N);

    gemm2_kernel<<<cdiv((long long)N * (N_CLASS / 2), B), B, 0, stream>>>(
        agg1, W2, V2, b2, dinv, xW2p, agg2, N);

    pull_ls<<<cdiv(N, 16), 320, 0, stream>>>(xW2p, csr, rowPtr, agg2, out, N);
}

// Round 8
// 294.427 us; speedup vs baseline: 1.6411x; 1.1403x over previous
//
#include <hip/hip_runtime.h>
#include <math.h>

// ARMA GNN forward: N=100000 nodes, E=1600000 edges, 64 -> 48 -> 40.
// out = log_softmax( relu( A @ (h1@W2) + h1@V2 + b2 ) ), h1 = relu( A @ (x@W1) + x@V1 + b1 )
// A = D^-1/2 (w) D^-1/2.
// R8: dense GEMMs on MFMA 16x16x32_bf16 (W|V concat as one B matrix, LDS-transposed
//     B-frags, fp32 accumulate). Kills the LDS-issue-bound scalar GEMM (~2.4 GB LDS
//     traffic -> ~12 ds_read_b128/wave). Everything else unchanged from R7.

constexpr int F_IN = 64;
constexpr int HIDDEN = 48;
constexpr int N_CLASS = 40;
constexpr int CHUNK = 8192;     // edges per binning block
constexpr int BIN_SHIFT = 9;    // 512 nodes per bin
constexpr int CSR_CAP = 12288;  // LDS stash cap in build_csr (avg bin ~8163)

typedef __attribute__((ext_vector_type(8))) short bf16x8;   // 4 VGPRs
typedef __attribute__((ext_vector_type(4))) float f32x4;    // acc frag

// ---- bf16 pack helpers (RNE) ----------------------------------------------
__device__ __forceinline__ short bfr(float f) {
    unsigned u = __float_as_uint(f);
    return (short)((u + 0x7fffu + ((u >> 16) & 1u)) >> 16);
}
__device__ __forceinline__ unsigned pack_bf2(float a, float b) {
    unsigned ua = __float_as_uint(a), ub = __float_as_uint(b);
    ua = (ua + 0x7fffu + ((ua >> 16) & 1u)) >> 16;
    ub = (ub + 0x7fffu + ((ub >> 16) & 1u)) >> 16;
    return ua | (ub << 16);
}
__device__ __forceinline__ float2 unpack_bf2(unsigned u) {
    return make_float2(__uint_as_float(u << 16), __uint_as_float(u & 0xffff0000u));
}
__device__ __forceinline__ bf16x8 cvt8(float4 f0, float4 f1) {
    bf16x8 r;
    r[0] = bfr(f0.x); r[1] = bfr(f0.y); r[2] = bfr(f0.z); r[3] = bfr(f0.w);
    r[4] = bfr(f1.x); r[5] = bfr(f1.y); r[6] = bfr(f1.z); r[7] = bfr(f1.w);
    return r;
}

// ============================================================================
// MFMA layer-1 GEMM body: 64 nodes/block, 96 cols (W1|V1), K=64.
// A[m=lane&15][k=quad*8+j] from x (fp32->bf16); B[k][n=lane&15][k=quad*8+j]
// from LDS-transposed Wcat; C/D: col=lane&15, row=quad*4+reg.
// smem layout: [0,12288) short WcatT[96][64]; [12288,36864) float ep[64][96].
// ============================================================================
__device__ __forceinline__ void mfma_gemm1_body(char* smem, const float* __restrict__ X,
                                                const float* __restrict__ W,
                                                const float* __restrict__ V,
                                                const float* __restrict__ b,
                                                unsigned* __restrict__ XWp,
                                                float* __restrict__ AGG, int N, int gb,
                                                int tid) {
    short* sWT = (short*)smem;                 // [96][64]
    float* ep = (float*)(smem + 12288);        // [64][96]
    // stage Wcat^T in bf16
    for (int i = tid; i < 96 * 64; i += 256) {
        int c = i >> 6, k = i & 63;
        float v = (c < 48) ? W[k * 48 + c] : V[k * 48 + (c - 48)];
        sWT[i] = bfr(v);
    }
    __syncthreads();

    int lane = tid & 63, wv = tid >> 6;
    int m = lane & 15, quad = lane >> 4;
    int nb0 = gb * 64;
    int n = nb0 + wv * 16 + m;

    bf16x8 a0, a1;
    if (n < N) {
        const float4* xr = (const float4*)(X + (size_t)n * 64 + quad * 8);
        a0 = cvt8(xr[0], xr[1]);
        const float4* xr2 = (const float4*)(X + (size_t)n * 64 + 32 + quad * 8);
        a1 = cvt8(xr2[0], xr2[1]);
    } else {
        for (int j = 0; j < 8; ++j) { a0[j] = 0; a1[j] = 0; }
    }

    f32x4 acc[6];
#pragma unroll
    for (int ct = 0; ct < 6; ++ct) acc[ct] = (f32x4){0.f, 0.f, 0.f, 0.f};
#pragma unroll
    for (int ct = 0; ct < 6; ++ct) {
        bf16x8 b0 = *(const bf16x8*)(sWT + (ct * 16 + m) * 64 + quad * 8);
        bf16x8 b1 = *(const bf16x8*)(sWT + (ct * 16 + m) * 64 + 32 + quad * 8);
        acc[ct] = __builtin_amdgcn_mfma_f32_16x16x32_bf16(a0, b0, acc[ct], 0, 0, 0);
        acc[ct] = __builtin_amdgcn_mfma_f32_16x16x32_bf16(a1, b1, acc[ct], 0, 0, 0);
    }
    // C-frag -> LDS epilogue buffer
#pragma unroll
    for (int ct = 0; ct < 6; ++ct)
#pragma unroll
        for (int r = 0; r < 4; ++r)
            ep[(wv * 16 + quad * 4 + r) * 96 + ct * 16 + m] = acc[ct][r];
    __syncthreads();
    // write out: cols 0..47 -> packed bf16 xWp ; cols 48..95 -> AGG (+bias)
    for (int i = tid; i < 64 * 24; i += 256) {
        int r = i / 24, c2 = i - r * 24;
        int node = nb0 + r;
        if (node >= N) continue;
        float w0 = ep[r * 96 + 2 * c2], w1 = ep[r * 96 + 2 * c2 + 1];
        XWp[node * 24 + c2] = pack_bf2(w0, w1);
        float v0 = ep[r * 96 + 48 + 2 * c2], v1 = ep[r * 96 + 48 + 2 * c2 + 1];
        float2 bb = ((const float2*)b)[c2];
        ((float2*)AGG)[node * 24 + c2] = make_float2(v0 + bb.x, v1 + bb.y);
    }
}

// ---- phase A: bin counting (LDS hist -> consecutive-addr atomics) + gemm1 --
__global__ __launch_bounds__(256) void count_gemm1(
    const int* __restrict__ dst, int* __restrict__ binCnt, int E, int nCountBlocks,
    const float* __restrict__ X, const float* __restrict__ W,
    const float* __restrict__ V, const float* __restrict__ b,
    unsigned* __restrict__ XWp, float* __restrict__ AGG, int N) {
    __shared__ char smem[36864];
    if ((int)blockIdx.x < nCountBlocks) {
        int* hist = (int*)smem;
        int tid = threadIdx.x;
        hist[tid] = 0;
        __syncthreads();
        long long e0 = (long long)blockIdx.x * CHUNK;
        int M = (int)min((long long)CHUNK, (long long)E - e0);
        for (int i = tid; i < M; i += 256) atomicAdd(&hist[dst[e0 + i] >> BIN_SHIFT], 1);
        __syncthreads();
        atomicAdd(&binCnt[tid], hist[tid]);  // consecutive words -> coalesced
    } else {
        mfma_gemm1_body(smem, X, W, V, b, XWp, AGG, N,
                        (int)blockIdx.x - nCountBlocks, (int)threadIdx.x);
    }
}

// ---- phase B: exclusive scan of 256 bin counts -----------------------------
__global__ void scan_bins(const int* __restrict__ binCnt, int* __restrict__ binStart,
                          int* __restrict__ binCursor, int* __restrict__ rowPtr,
                          int E, int N) {
    __shared__ int s[256];
    int t = threadIdx.x;
    int v = binCnt[t];
    s[t] = v;
    __syncthreads();
#pragma unroll
    for (int o = 1; o < 256; o <<= 1) {
        int u = (t >= o) ? s[t - o] : 0;
        __syncthreads();
        s[t] += u;
        __syncthreads();
    }
    int excl = s[t] - v;
    binStart[t] = excl;
    binCursor[t] = excl;
    if (t == 0) {
        binStart[256] = E;
        rowPtr[N] = E;
    }
}

// ---- phase C: scatter edges into bin regions (256B runs, line-coalesced) ---
__global__ void binscatter(const int* __restrict__ src, const int* __restrict__ dst,
                           const float* __restrict__ w, int* __restrict__ binCursor,
                           int2* __restrict__ binned, int E) {
    __shared__ int sx[CHUNK];
    __shared__ int sw[CHUNK];
    __shared__ unsigned char sbin[CHUNK];
    __shared__ int hist[256];
    int tid = threadIdx.x;
    hist[tid] = 0;
    __syncthreads();
    long long e0 = (long long)blockIdx.x * CHUNK;
    int M = (int)min((long long)CHUNK, (long long)E - e0);
    for (int i = tid; i < M; i += 256) {
        int d = dst[e0 + i];
        int bn = d >> BIN_SHIFT;
        sx[i] = ((d & 511) << 17) | src[e0 + i];
        sw[i] = __float_as_int(w[e0 + i]);
        sbin[i] = (unsigned char)bn;
        atomicAdd(&hist[bn], 1);
    }
    __syncthreads();
    int base = atomicAdd(&binCursor[tid], hist[tid]);  // consecutive words -> coalesced
    __syncthreads();
    hist[tid] = base;  // reuse as global cursor
    __syncthreads();
    for (int i = tid; i < M; i += 256) {
        int p = atomicAdd(&hist[sbin[i]], 1);  // LDS atomic, cheap
        binned[p] = make_int2(sx[i], sw[i]);
    }
}

// ---- phase D: per-bin LDS counting sort -> CSR (w pre-scaled by dinv[dst]) -
__global__ __launch_bounds__(512) void build_csr(const int2* __restrict__ binned,
                                                 const int* __restrict__ binStart,
                                                 int* __restrict__ rowPtr,
                                                 float* __restrict__ dinv,
                                                 int2* __restrict__ csr, int N) {
    __shared__ int sx[CSR_CAP];
    __shared__ int sw[CSR_CAP];
    __shared__ int cntL[512];
    __shared__ float degL[512];  // deg sums, then dinv values
    __shared__ int scanL[512];
    int b = blockIdx.x, tid = threadIdx.x;
    int e0 = binStart[b], e1 = binStart[b + 1], M = e1 - e0;
    cntL[tid] = 0;
    degL[tid] = 0.f;
    __syncthreads();
    bool fits = (M <= CSR_CAP);
    for (int i = tid; i < M; i += 512) {
        int2 p = binned[e0 + i];
        if (fits) { sx[i] = p.x; sw[i] = p.y; }
        int dl = ((unsigned)p.x) >> 17;
        atomicAdd(&cntL[dl], 1);
        atomicAdd(&degL[dl], __int_as_float(p.y));
    }
    __syncthreads();
    int v = cntL[tid];
    scanL[tid] = v;
    __syncthreads();
#pragma unroll
    for (int o = 1; o < 512; o <<= 1) {
        int u = (tid >= o) ? scanL[tid - o] : 0;
        __syncthreads();
        scanL[tid] += u;
        __syncthreads();
    }
    int excl = scanL[tid] - v;
    int node = (b << BIN_SHIFT) + tid;
    float dg = degL[tid];
    float dv = dg > 0.f ? rsqrtf(dg) : 0.f;
    if (node < N) {
        rowPtr[node] = e0 + excl;
        dinv[node] = dv;
    }
    cntL[tid] = e0 + excl;  // reuse as global write cursor
    degL[tid] = dv;         // reuse as dinv table for write phase
    __syncthreads();
    for (int i = tid; i < M; i += 512) {
        int px, pw;
        if (fits) { px = sx[i]; pw = sw[i]; }
        else { int2 p = binned[e0 + i]; px = p.x; pw = p.y; }
        int dl = ((unsigned)px) >> 17;
        int pos = atomicAdd(&cntL[dl], 1);  // LDS atomic
        float wn = __int_as_float(pw) * degL[dl];  // fold dinv[dst] in now
        csr[pos] = make_int2(px & 0x1FFFF, __float_as_int(wn));
    }
}

// ---- xWp[n][*] *= dinv[n]  (layer-1; layer-2 scaling fused in gemm2) -------
template <int C2>
__global__ void scale_xw(unsigned* __restrict__ XWp, const float* __restrict__ dinv,
                         int total) {
    int t = blockIdx.x * blockDim.x + threadIdx.x;
    if (t >= total) return;
    float dv = dinv[t / C2];
    float2 u = unpack_bf2(XWp[t]);
    XWp[t] = pack_bf2(u.x * dv, u.y * dv);
}

// ============================================================================
// MFMA layer-2 GEMM: 64 nodes/block, 80 cols (W2|V2), K=48 zero-padded to 64.
// A = relu(agg1) fp32->bf16. xW2p written dinv-scaled.
// smem: [0,10240) short WT2[80][64]; [10240,30720) float ep[64][80].
// ============================================================================
__global__ __launch_bounds__(256) void gemm2_kernel(
    const float* __restrict__ X, const float* __restrict__ W,
    const float* __restrict__ V, const float* __restrict__ b,
    const float* __restrict__ dinv, unsigned* __restrict__ XWp,
    float* __restrict__ AGG, int N) {
    __shared__ char smem[30720];
    short* sWT = (short*)smem;            // [80][64], k>=48 zero
    float* ep = (float*)(smem + 10240);   // [64][80]
    int tid = threadIdx.x;
    for (int i = tid; i < 80 * 64; i += 256) {
        int c = i >> 6, k = i & 63;
        float v = 0.f;
        if (k < 48) v = (c < 40) ? W[k * 40 + c] : V[k * 40 + (c - 40)];
        sWT[i] = bfr(v);
    }
    __syncthreads();

    int lane = tid & 63, wv = tid >> 6;
    int m = lane & 15, quad = lane >> 4;
    int nb0 = (int)blockIdx.x * 64;
    int n = nb0 + wv * 16 + m;

    bf16x8 a0, a1;
    if (n < N) {
        const float4* xr = (const float4*)(X + (size_t)n * 48 + quad * 8);
        float4 f0 = xr[0], f1 = xr[1];
        f0.x = fmaxf(f0.x, 0.f); f0.y = fmaxf(f0.y, 0.f);
        f0.z = fmaxf(f0.z, 0.f); f0.w = fmaxf(f0.w, 0.f);
        f1.x = fmaxf(f1.x, 0.f); f1.y = fmaxf(f1.y, 0.f);
        f1.z = fmaxf(f1.z, 0.f); f1.w = fmaxf(f1.w, 0.f);
        a0 = cvt8(f0, f1);
        if (quad < 2) {  // k = 32 + quad*8 + j in [32,48)
            const float4* xr2 = (const float4*)(X + (size_t)n * 48 + 32 + quad * 8);
            float4 g0 = xr2[0], g1 = xr2[1];
            g0.x = fmaxf(g0.x, 0.f); g0.y = fmaxf(g0.y, 0.f);
            g0.z = fmaxf(g0.z, 0.f); g0.w = fmaxf(g0.w, 0.f);
            g1.x = fmaxf(g1.x, 0.f); g1.y = fmaxf(g1.y, 0.f);
            g1.z = fmaxf(g1.z, 0.f); g1.w = fmaxf(g1.w, 0.f);
            a1 = cvt8(g0, g1);
        } else {
            for (int j = 0; j < 8; ++j) a1[j] = 0;
        }
    } else {
        for (int j = 0; j < 8; ++j) { a0[j] = 0; a1[j] = 0; }
    }

    f32x4 acc[5];
#pragma unroll
    for (int ct = 0; ct < 5; ++ct) acc[ct] = (f32x4){0.f, 0.f, 0.f, 0.f};
#pragma unroll
    for (int ct = 0; ct < 5; ++ct) {
        bf16x8 b0 = *(const bf16x8*)(sWT + (ct * 16 + m) * 64 + quad * 8);
        bf16x8 b1 = *(const bf16x8*)(sWT + (ct * 16 + m) * 64 + 32 + quad * 8);
        acc[ct] = __builtin_amdgcn_mfma_f32_16x16x32_bf16(a0, b0, acc[ct], 0, 0, 0);
        acc[ct] = __builtin_amdgcn_mfma_f32_16x16x32_bf16(a1, b1, acc[ct], 0, 0, 0);
    }
#pragma unroll
    for (int ct = 0; ct < 5; ++ct)
#pragma unroll
        for (int r = 0; r < 4; ++r)
            ep[(wv * 16 + quad * 4 + r) * 80 + ct * 16 + m] = acc[ct][r];
    __syncthreads();
    for (int i = tid; i < 64 * 20; i += 256) {
        int r = i / 20, c2 = i - r * 20;
        int node = nb0 + r;
        if (node >= N) continue;
        float dv = dinv[node];
        float w0 = ep[r * 80 + 2 * c2], w1 = ep[r * 80 + 2 * c2 + 1];
        XWp[node * 20 + c2] = pack_bf2(w0 * dv, w1 * dv);
        float v0 = ep[r * 80 + 40 + 2 * c2], v1 = ep[r * 80 + 40 + 2 * c2 + 1];
        float2 bb = ((const float2*)b)[c2];
        ((float2*)AGG)[node * 20 + c2] = make_float2(v0 + bb.x, v1 + bb.y);
    }
}

// ---- 4-way unrolled row accumulate (xWp pre-scaled; csr.y = w*dinv[dst]) ---
template <int C2>
__device__ __forceinline__ float2 row_accum(const unsigned* __restrict__ XWp,
                                            const int2* __restrict__ csr, int j,
                                            int end, int c2, float2 s) {
    for (; j + 4 <= end; j += 4) {
        int2 p0 = csr[j], p1 = csr[j + 1], p2 = csr[j + 2], p3 = csr[j + 3];
        unsigned u0 = XWp[p0.x * C2 + c2];
        unsigned u1 = XWp[p1.x * C2 + c2];
        unsigned u2 = XWp[p2.x * C2 + c2];
        unsigned u3 = XWp[p3.x * C2 + c2];
        float2 x0 = unpack_bf2(u0), x1 = unpack_bf2(u1);
        float2 x2 = unpack_bf2(u2), x3 = unpack_bf2(u3);
        float n0 = __int_as_float(p0.y), n1 = __int_as_float(p1.y);
        float n2 = __int_as_float(p2.y), n3 = __int_as_float(p3.y);
        s.x = fmaf(x0.x, n0, s.x); s.y = fmaf(x0.y, n0, s.y);
        s.x = fmaf(x1.x, n1, s.x); s.y = fmaf(x1.y, n1, s.y);
        s.x = fmaf(x2.x, n2, s.x); s.y = fmaf(x2.y, n2, s.y);
        s.x = fmaf(x3.x, n3, s.x); s.y = fmaf(x3.y, n3, s.y);
    }
    for (; j < end; ++j) {
        int2 p = csr[j];
        float2 xw = unpack_bf2(XWp[p.x * C2 + c2]);
        float nr = __int_as_float(p.y);
        s.x = fmaf(xw.x, nr, s.x);
        s.y = fmaf(xw.y, nr, s.y);
    }
    return s;
}

// ---- layer-1 pull: AGG[n] += sum_j xWp[src_j] * nrm_j ----------------------
template <int C>
__global__ void pull_agg(const unsigned* __restrict__ XWp, const int2* __restrict__ csr,
                         const int* __restrict__ rowPtr, float* __restrict__ AGG, int N) {
    constexpr int C2 = C / 2;
    int t = blockIdx.x * blockDim.x + threadIdx.x;
    if (t >= N * C2) return;
    int n = t / C2, c2 = t - n * C2;
    float2 s = ((const float2*)AGG)[t];
    s = row_accum<C2>(XWp, csr, rowPtr[n], rowPtr[n + 1], c2, s);
    ((float2*)AGG)[t] = s;
}

// ---- layer-2 pull fused with log_softmax(relu(.)) --------------------------
__global__ __launch_bounds__(320) void pull_ls(const unsigned* __restrict__ XWp,
                                               const int2* __restrict__ csr,
                                               const int* __restrict__ rowPtr,
                                               const float* __restrict__ AGGin,
                                               float* __restrict__ out, int N) {
    constexpr int C2 = N_CLASS / 2;  // 20
    __shared__ float2 sbuf[16 * C2];
    __shared__ float sl[16];
    int tid = threadIdx.x;
    int nl = tid / C2, c2 = tid - nl * C2;
    int n = blockIdx.x * 16 + nl;
    float2 s = make_float2(0.f, 0.f);
    if (n < N) {
        s = ((const float2*)AGGin)[n * C2 + c2];
        s = row_accum<C2>(XWp, csr, rowPtr[n], rowPtr[n + 1], c2, s);
    }
    sbuf[tid] = s;
    __syncthreads();
    if (tid < 16) {
        const float2* row = sbuf + tid * C2;
        float m = 0.f;  // relu floor
        for (int k = 0; k < C2; ++k) {
            float2 v = row[k];
            m = fmaxf(m, fmaxf(v.x, v.y));
        }
        float sum = 0.f;
        for (int k = 0; k < C2; ++k) {
            float2 v = row[k];
            sum += expf(fmaxf(v.x, 0.f) - m) + expf(fmaxf(v.y, 0.f) - m);
        }
        sl[tid] = m + logf(sum);
    }
    __syncthreads();
    if (n < N) {
        float l = sl[nl];
        ((float2*)out)[n * C2 + c2] =
            make_float2(fmaxf(s.x, 0.f) - l, fmaxf(s.y, 0.f) - l);
    }
}

extern "C" void kernel_launch(void* const* d_in, const int* in_sizes, int n_in,
                              void* d_out, int out_size, void* d_ws, size_t ws_size,
                              hipStream_t stream) {
    const float* x  = (const float*)d_in[0];
    const int*   ei = (const int*)d_in[1];
    const float* ew = (const float*)d_in[2];
    const float* W1 = (const float*)d_in[3];
    const float* V1 = (const float*)d_in[4];
    const float* b1 = (const float*)d_in[5];
    const float* W2 = (const float*)d_in[6];
    const float* V2 = (const float*)d_in[7];
    const float* b2 = (const float*)d_in[8];
    float* out = (float*)d_out;

    const int N = in_sizes[0] / F_IN;
    const int E = in_sizes[2];
    const int* src = ei;
    const int* dst = ei + E;

    char* ws = (char*)d_ws;
    size_t off = 0;
    auto carve = [&](size_t bytes) {
        void* p = ws + off;
        off = (off + bytes + 255) & ~size_t(255);
        return p;
    };
    int*      binCnt    = (int*)carve(256 * 4);
    int*      binStart  = (int*)carve(257 * 4);
    int*      binCursor = (int*)carve(256 * 4);
    int*      rowPtr    = (int*)carve((size_t)(N + 1) * 4);
    float*    dinv      = (float*)carve((size_t)N * 4);
    int2*     binned    = (int2*)carve((size_t)E * 8);
    int2*     csr       = (int2*)carve((size_t)E * 8);
    unsigned* xW1p      = (unsigned*)carve((size_t)N * (HIDDEN / 2) * 4);  // bf16x2
    float*    agg1      = (float*)carve((size_t)N * HIDDEN * 4);
    float*    agg2      = (float*)carve((size_t)N * N_CLASS * 4);
    unsigned* xW2p      = xW1p;  // xW1p dead before gemm2 writes

    const int B = 256;
    auto cdiv = [](long long a, long long b) { return (int)((a + b - 1) / b); };
    const int nChunks = cdiv(E, CHUNK);
    const int nBins = (N + (1 << BIN_SHIFT) - 1) >> BIN_SHIFT;
    const int nGemmBlocks = cdiv(N, 64);

    hipMemsetAsync(binCnt, 0, 256 * 4, stream);

    count_gemm1<<<nChunks + nGemmBlocks, B, 0, stream>>>(dst, binCnt, E, nChunks,
                                                         x, W1, V1, b1, xW1p, agg1, N);
    scan_bins<<<1, 256, 0, stream>>>(binCnt, binStart, binCursor, rowPtr, E, N);
    binscatter<<<nChunks, B, 0, stream>>>(src, dst, ew, binCursor, binned, E);
    build_csr<<<nBins, 512, 0, stream>>>(binned, binStart, rowPtr, dinv, csr, N);

    scale_xw<HIDDEN / 2><<<cdiv((long long)N * (HIDDEN / 2), B), B, 0, stream>>>(
        xW1p, dinv, N * (HIDDEN / 2));

    pull_agg<HIDDEN><<<cdiv((long long)N * (HIDDEN / 2), B), B, 0, stream>>>(
        xW1p, csr, rowPtr, agg1, N);

    gemm2_kernel<<<nGemmBlocks, B, 0, stream>>>(agg1, W2, V2, b2, dinv, xW2p, agg2, N);

    pull_ls<<<cdiv(N, 16), 320, 0, stream>>>(xW2p, csr, rowPtr, agg2, out, N);
}